// Round 6
// baseline (231.321 us; speedup 1.0000x reference)
//
#include <hip/hip_runtime.h>
#include <math.h>

#define BB 32
#define NN 8732
#define CC 21
#define TOPK 200
#define NPOSE 32
#define NLINE 3
#define NBINS 2048
#define CAP 1024
#define ROWW 40

// ---------------------------------------------------------------------------
// Fast f64 exp, |rel err| ~1e-15: f32-rounds identically to libm exp except
// with prob ~2e-8/call (1 ulp, matters only on exact rank ties).
// ---------------------------------------------------------------------------
__device__ __forceinline__ double fexp(double x) {
  const double LOG2E = 1.4426950408889634074;
  const double LN2HI = 6.93147180369123816490e-01;
  const double LN2LO = 1.90821492927058770002e-10;
  double kd = rint(x * LOG2E);
  double r = fma(-kd, LN2HI, x);
  r = fma(-kd, LN2LO, r);
  double p = 2.08767569878680989792e-09;
  p = fma(p, r, 2.50521083854417187751e-08);
  p = fma(p, r, 2.75573192239858906526e-07);
  p = fma(p, r, 2.75573192239858925110e-06);
  p = fma(p, r, 2.48015873015873015873e-05);
  p = fma(p, r, 1.98412698412698412698e-04);
  p = fma(p, r, 1.38888888888888888889e-03);
  p = fma(p, r, 8.33333333333333333333e-03);
  p = fma(p, r, 4.16666666666666666667e-02);
  p = fma(p, r, 1.66666666666666666667e-01);
  p = fma(p, r, 0.5);
  p = fma(p, r, 1.0);
  p = fma(p, r, 1.0);
  int k = (int)kd;
  k = k < -1020 ? -1020 : (k > 1020 ? 1020 : k);
  double sc = __longlong_as_double((long long)(1023 + k) << 52);
  return p * sc;  // exact pow2 mul == ldexp(p,k)
}

// ---------------------------------------------------------------------------
// aux[b*NN+n] = (rowmax, pairwise-8 sum of f32-rounded exps) — the exact-f32
// softmax stats. Coalesced float4 staging through LDS.
// ---------------------------------------------------------------------------
__global__ __launch_bounds__(256) void aux_kernel(
    const float* __restrict__ conf, float2* __restrict__ aux) {
  __shared__ __align__(16) float buf[256 * CC];
  const int tid = threadIdx.x;
  const int i0 = blockIdx.x * 256;
  const int base = i0 * CC;
  int total = BB * NN * CC - base;
  if (total > 256 * CC) total = 256 * CC;
  {
    const float4* g4 = (const float4*)(conf + base);
    float4* b4 = (float4*)buf;
    const int n4 = total >> 2;  // base and total are multiples of 4
    for (int t = tid; t < n4; t += 256) b4[t] = g4[t];
  }
  __syncthreads();
  const int i = i0 + tid;
  if (i >= BB * NN) return;
  const float* p = buf + tid * CC;  // stride 21 (odd): 2-way LDS alias = free
  float m = p[0];
#pragma unroll
  for (int c = 1; c < CC; ++c) m = fmaxf(m, p[c]);
  float e[CC];
#pragma unroll 1
  for (int c = 0; c < CC; ++c) e[c] = (float)fexp((double)(p[c] - m));
  float r0 = e[0] + e[8], r1 = e[1] + e[9], r2 = e[2] + e[10], r3 = e[3] + e[11];
  float r4 = e[4] + e[12], r5 = e[5] + e[13], r6 = e[6] + e[14], r7 = e[7] + e[15];
  float sum = ((r0 + r1) + (r2 + r3)) + ((r4 + r5) + (r6 + r7));
  sum += e[16]; sum += e[17]; sum += e[18]; sum += e[19]; sum += e[20];
  aux[i] = make_float2(m, sum);
}

__device__ __forceinline__ int score_bin(float s) {
  unsigned u = __float_as_uint(s);
  int bin = (int)(u >> 15) - 30720;
  return bin < 0 ? 0 : (bin > NBINS - 1 ? NBINS - 1 : bin);
}

// Mode-0 fallback: full softmax score for (b,n,c) straight from conf.
__device__ __forceinline__ float score_full(const float* conf, int b, int c, int n) {
  const float* p = conf + ((size_t)b * NN + n) * CC;
  float mm = p[0];
  for (int c2 = 1; c2 < CC; ++c2) mm = fmaxf(mm, p[c2]);
  float e[CC];
  for (int c2 = 0; c2 < CC; ++c2) e[c2] = (float)fexp((double)(p[c2] - mm));
  float r0 = e[0] + e[8], r1 = e[1] + e[9], r2 = e[2] + e[10], r3 = e[3] + e[11];
  float r4 = e[4] + e[12], r5 = e[5] + e[13], r6 = e[6] + e[14], r7 = e[7] + e[15];
  float sum = ((r0 + r1) + (r2 + r3)) + ((r4 + r5) + (r6 + r7));
  sum += e[16]; sum += e[17]; sum += e[18]; sum += e[19]; sum += e[20];
  return e[c] / sum;
}

// ---------------------------------------------------------------------------
// One block per (b,c): fused score + single-pass top-200 + parallel IoU
// matrix + fast-path greedy bit-scan + row assembly.
// ---------------------------------------------------------------------------
__global__ __launch_bounds__(256) void nms_kernel(
    const float* __restrict__ loc, const float* __restrict__ conf,
    const float* __restrict__ pose, const float* __restrict__ line,
    const float* __restrict__ dbox, const float2* __restrict__ aux,
    int mode, float* __restrict__ out) {
  const int bc = blockIdx.x;
  const int b = bc / CC, c = bc - b * CC;
  const int tid = threadIdx.x;
  const int wv = tid >> 6, lane = tid & 63;
  float* outSlab = out + (size_t)bc * (TOPK * ROWW);
  const float4 z4 = make_float4(0.f, 0.f, 0.f, 0.f);

  if (c == 0) {  // out.at[:, 0].set(0.0)
    float4* o4 = (float4*)outSlab;
    for (int i = tid; i < TOPK * ROWW / 4; i += 256) o4[i] = z4;
    return;
  }

  __shared__ int hist[NBINS];
  __shared__ float cscore[CAP];
  __shared__ int cidx[CAP];
  __shared__ float bx1[TOPK], by1[TOPK], bx2[TOPK], by2[TOPK], barea[TOPK];
  __shared__ unsigned long long supp[TOPK * 4];  // IoU>thr bits, l>j only
  __shared__ unsigned long long rowAnyBits[4];
  __shared__ int kept[TOPK];
  __shared__ int waveTot[4];
  __shared__ int sBT, sCnt, sKept;

  for (int i = tid; i < NBINS; i += 256) hist[i] = 0;
  if (tid == 0) { sCnt = 0; sBT = 0; }
  __syncthreads();

  const float2* auxB = aux + (size_t)b * NN;
  const float* confB = conf + (size_t)b * NN * CC + c;

  // ---- fused scoring: 36 scores per thread into registers ----
  float s36[36];
  if (mode == 1) {
#pragma unroll
    for (int k = 0; k < 9; ++k) {
      const int n0 = k * 1024 + (tid << 2);
      if (k < 8 || tid < 135) {  // 8732-8192=540=135*4
        float4 a01 = *(const float4*)(auxB + n0);      // aux[n0], aux[n0+1]
        float4 a23 = *(const float4*)(auxB + n0 + 2);  // aux[n0+2], aux[n0+3]
        float c0 = confB[(size_t)(n0 + 0) * CC];
        float c1 = confB[(size_t)(n0 + 1) * CC];
        float c2 = confB[(size_t)(n0 + 2) * CC];
        float c3 = confB[(size_t)(n0 + 3) * CC];
        s36[k * 4 + 0] = (float)fexp((double)(c0 - a01.x)) / a01.y;
        s36[k * 4 + 1] = (float)fexp((double)(c1 - a01.z)) / a01.w;
        s36[k * 4 + 2] = (float)fexp((double)(c2 - a23.x)) / a23.y;
        s36[k * 4 + 3] = (float)fexp((double)(c3 - a23.z)) / a23.w;
      } else {
        s36[k * 4 + 0] = -1.f; s36[k * 4 + 1] = -1.f;
        s36[k * 4 + 2] = -1.f; s36[k * 4 + 3] = -1.f;
      }
    }
  } else {
#pragma unroll 1
    for (int k = 0; k < 9; ++k) {
      const int n0 = k * 1024 + (tid << 2);
      if (k < 8 || tid < 135) {
        for (int q = 0; q < 4; ++q) s36[k * 4 + q] = score_full(conf, b, c, n0 + q);
      } else {
        for (int q = 0; q < 4; ++q) s36[k * 4 + q] = -1.f;
      }
    }
  }

  // ---- histogram on f32 score bit-pattern (monotone for s>0) ----
#pragma unroll
  for (int k2 = 0; k2 < 36; ++k2) {
    float s = s36[k2];
    if (s > 0.01f) atomicAdd(&hist[score_bin(s)], 1);
  }
  __syncthreads();

  // ---- parallel threshold-bin: wave suffix-scan + crossing thread ----
  int s8 = 0;
#pragma unroll
  for (int k = 0; k < 8; ++k) s8 += hist[tid * 8 + k];
  int cs = s8;
#pragma unroll
  for (int d = 1; d < 64; d <<= 1) {
    int t = __shfl_down(cs, d, 64);
    if (lane + d < 64) cs += t;
  }
  if (lane == 0) waveTot[wv] = cs;
  __syncthreads();
  {
    int higher = 0;
    for (int g = wv + 1; g < 4; ++g) higher += waveTot[g];
    int incl = cs + higher;
    int excl = incl - s8;
    if (excl < TOPK && incl >= TOPK) {  // unique crossing thread
      int cum = excl, bt = tid * 8;
      for (int bin = tid * 8 + 7;; --bin) {
        cum += hist[bin];
        if (cum >= TOPK || bin == tid * 8) { bt = bin; break; }
      }
      sBT = bt;
    }
  }
  __syncthreads();
  const int bt = sBT;

  // ---- collect candidates from registers ----
#pragma unroll
  for (int k2 = 0; k2 < 36; ++k2) {
    float s = s36[k2];
    if (s > 0.01f && score_bin(s) >= bt) {
      int p = atomicAdd(&sCnt, 1);
      if (p < CAP) {
        cscore[p] = s;
        cidx[p] = (k2 >> 2) * 1024 + (tid << 2) + (k2 & 3);
      }
    }
  }
  __syncthreads();
  const int M = sCnt < CAP ? sCnt : CAP;
  if (M == 0) {
    float4* o4 = (float4*)outSlab;
    for (int i = tid; i < TOPK * ROWW / 4; i += 256) o4[i] = z4;
    return;
  }

  // ---- bitonic sort by (score desc, idx asc) — lax.top_k tie semantics ----
  int P = 1;
  while (P < M) P <<= 1;
  for (int i = M + tid; i < P; i += 256) {
    cscore[i] = -1e30f;
    cidx[i] = 0x7fffffff;
  }
  __syncthreads();
  for (int k = 2; k <= P; k <<= 1) {
    for (int j = k >> 1; j > 0; j >>= 1) {
      for (int i = tid; i < P; i += 256) {
        int ixj = i ^ j;
        if (ixj > i) {
          float si = cscore[i], sj = cscore[ixj];
          int ii = cidx[i], ij = cidx[ixj];
          bool agt = (si > sj) || (si == sj && ii < ij);
          bool up = ((i & k) == 0);
          if (up ? !agt : agt) {
            cscore[i] = sj; cscore[ixj] = si;
            cidx[i] = ij;  cidx[ixj] = ii;
          }
        }
      }
      __syncthreads();
    }
  }

  const int K = M < TOPK ? M : TOPK;

  // ---- decode candidate boxes, f32, reference op order ----
  const float* locB = loc + (size_t)b * NN * 4;
  for (int t = tid; t < K; t += 256) {
    int n = cidx[t];
    float l0 = locB[(size_t)n * 4 + 0], l1 = locB[(size_t)n * 4 + 1];
    float l2 = locB[(size_t)n * 4 + 2], l3 = locB[(size_t)n * 4 + 3];
    float d0 = dbox[(size_t)n * 4 + 0], d1 = dbox[(size_t)n * 4 + 1];
    float d2 = dbox[(size_t)n * 4 + 2], d3 = dbox[(size_t)n * 4 + 3];
    float cx = d0 + (l0 * 0.1f) * d2;
    float cy = d1 + (l1 * 0.1f) * d3;
    float w = d2 * (float)fexp((double)(l2 * 0.2f));
    float h = d3 * (float)fexp((double)(l3 * 0.2f));
    float x1 = cx - w * 0.5f;
    float y1 = cy - h * 0.5f;
    float x2 = x1 + w;
    float y2 = y1 + h;
    bx1[t] = x1; by1[t] = y1; bx2[t] = x2; by2[t] = y2;
    barea[t] = (x2 - x1) * (y2 - y1);
  }
  __syncthreads();

  // ---- parallel suppression matrix: wave wv owns 64-lane word wv ----
  {
    const int l = wv * 64 + lane;
    float lx1 = 0.f, ly1 = 0.f, lx2 = 0.f, ly2 = 0.f, lar = 0.f;
    const bool lvalid = l < K;
    if (lvalid) { lx1 = bx1[l]; ly1 = by1[l]; lx2 = bx2[l]; ly2 = by2[l]; lar = barea[l]; }
    const int wtop = wv * 64 + 63;
    for (int j = 0; j < K; ++j) {
      unsigned long long mres = 0;
      if (wtop > j) {  // wave-uniform
        float jx1 = bx1[j], jy1 = by1[j], jx2 = bx2[j], jy2 = by2[j], ja = barea[j];
        float xx1 = fmaxf(lx1, jx1);
        float yy1 = fmaxf(ly1, jy1);
        float xx2 = fminf(lx2, jx2);
        float yy2 = fminf(ly2, jy2);
        float iw = fmaxf(xx2 - xx1, 0.0f);
        float ih = fmaxf(yy2 - yy1, 0.0f);
        float inter = iw * ih;
        float uni = (lar - inter) + ja;         // area - inter + area[i]
        bool hit = lvalid & (l > j) & (inter / uni > 0.45f);
        mres = __ballot((int)hit);
      }
      if (lane == 0) supp[j * 4 + wv] = mres;   // always written (0 if skipped)
    }
  }
  __syncthreads();

  // ---- rowAny: which supp rows have any suppression bit (rare) ----
  {
    bool nz = false;
    if (tid < K)
      nz = (supp[tid * 4 + 0] | supp[tid * 4 + 1] |
            supp[tid * 4 + 2] | supp[tid * 4 + 3]) != 0ull;
    unsigned long long bal = __ballot((int)nz);
    if (lane == 0) rowAnyBits[wv] = bal;
  }
  __syncthreads();

  // ---- serial greedy with fast path: LDS reads only on suppressing rows ----
  if (tid == 0) {
    unsigned long long alive[4];
#pragma unroll
    for (int w = 0; w < 4; ++w) {
      int cnt = K - w * 64;
      alive[w] = cnt <= 0 ? 0ull : (cnt >= 64 ? ~0ull : ((1ull << cnt) - 1ull));
    }
    int nk = 0;
#pragma unroll
    for (int w = 0; w < 4; ++w) {
      const unsigned long long raw = rowAnyBits[w];
      while (alive[w]) {
        int bit = __ffsll(alive[w]) - 1;
        int j = w * 64 + bit;
        kept[nk++] = j;
        alive[w] &= ~(1ull << bit);
        if ((raw >> bit) & 1) {  // rare: row j suppresses someone
          unsigned long long r0 = supp[j * 4 + 0];
          unsigned long long r1 = supp[j * 4 + 1];
          unsigned long long r2 = supp[j * 4 + 2];
          unsigned long long r3 = supp[j * 4 + 3];
          alive[0] &= ~r0; alive[1] &= ~r1; alive[2] &= ~r2; alive[3] &= ~r3;
        }
      }
    }
    sKept = nk;
  }
  __syncthreads();

  // ---- write kept rows, then zero only the tail rows ----
  const int nk = sKept;
  const float* poseB = pose + (size_t)b * NN * NPOSE;
  const float* lineB = line + (size_t)b * NN * NLINE;
  for (int t = tid; t < nk; t += 256) {
    int j = kept[t];
    int n = cidx[j];
    float* row = outSlab + (size_t)t * ROWW;
    row[0] = cscore[j];
    row[1] = bx1[j];
    row[2] = by1[j];
    row[3] = bx2[j];
    row[4] = by2[j];
    const float4* p4 = (const float4*)(poseB + (size_t)n * NPOSE);
#pragma unroll
    for (int q = 0; q < 8; ++q) {
      float4 pv = p4[q];
      row[5 + 4 * q + 0] = pv.x;
      row[5 + 4 * q + 1] = pv.y;
      row[5 + 4 * q + 2] = pv.z;
      row[5 + 4 * q + 3] = pv.w;
    }
    row[37] = lineB[(size_t)n * NLINE + 0];
    row[38] = lineB[(size_t)n * NLINE + 1];
    row[39] = lineB[(size_t)n * NLINE + 2];
  }
  {  // rows [nk, TOPK): 10 float4 per row
    const int zq = (TOPK - nk) * 10;
    float4* o4 = (float4*)(outSlab + (size_t)nk * ROWW);
    for (int q = tid; q < zq; q += 256) o4[q] = z4;
  }
}

// ---------------------------------------------------------------------------
extern "C" void kernel_launch(void* const* d_in, const int* in_sizes, int n_in,
                              void* d_out, int out_size, void* d_ws, size_t ws_size,
                              hipStream_t stream) {
  const float* loc  = (const float*)d_in[0];
  const float* conf = (const float*)d_in[1];
  const float* pose = (const float*)d_in[2];
  const float* line = (const float*)d_in[3];
  const float* dbox = (const float*)d_in[4];
  float* out = (float*)d_out;

  const size_t auxBytes = (size_t)BB * NN * sizeof(float2);  // ~2.2 MB
  int mode = (ws_size >= auxBytes) ? 1 : 0;
  float2* aux = mode ? (float2*)d_ws : nullptr;

  if (mode) {
    const int total = BB * NN;
    aux_kernel<<<(total + 255) / 256, 256, 0, stream>>>(conf, aux);
  }
  nms_kernel<<<BB * CC, 256, 0, stream>>>(loc, conf, pose, line, dbox,
                                          aux, mode, out);
}

// Round 7
// 194.091 us; speedup vs baseline: 1.1918x; 1.1918x over previous
//
#include <hip/hip_runtime.h>
#include <math.h>

#define BB 32
#define NN 8732
#define CC 21
#define TOPK 200
#define NPOSE 32
#define NLINE 3
#define NBINS 2048
#define CAP 1024
#define ROWW 40

// ---------------------------------------------------------------------------
// Fast f64 exp, |rel err| ~1e-15: f32-rounds identically to libm exp except
// with prob ~2e-8/call (1 ulp, matters only on exact rank ties).
// ---------------------------------------------------------------------------
__device__ __forceinline__ double fexp(double x) {
  const double LOG2E = 1.4426950408889634074;
  const double LN2HI = 6.93147180369123816490e-01;
  const double LN2LO = 1.90821492927058770002e-10;
  double kd = rint(x * LOG2E);
  double r = fma(-kd, LN2HI, x);
  r = fma(-kd, LN2LO, r);
  double p = 2.08767569878680989792e-09;
  p = fma(p, r, 2.50521083854417187751e-08);
  p = fma(p, r, 2.75573192239858906526e-07);
  p = fma(p, r, 2.75573192239858925110e-06);
  p = fma(p, r, 2.48015873015873015873e-05);
  p = fma(p, r, 1.98412698412698412698e-04);
  p = fma(p, r, 1.38888888888888888889e-03);
  p = fma(p, r, 8.33333333333333333333e-03);
  p = fma(p, r, 4.16666666666666666667e-02);
  p = fma(p, r, 1.66666666666666666667e-01);
  p = fma(p, r, 0.5);
  p = fma(p, r, 1.0);
  p = fma(p, r, 1.0);
  int k = (int)kd;
  k = k < -1020 ? -1020 : (k > 1020 ? 1020 : k);
  double sc = __longlong_as_double((long long)(1023 + k) << 52);
  return p * sc;  // exact pow2 mul == ldexp(p,k)
}

// ---------------------------------------------------------------------------
// scores[b][c][n] = softmax(conf)[b][n][c]; exact-f32 pipeline (f32 max,
// f32-rounded exp of f32 diff, numpy pairwise-8 sum, true f32 divide).
// Transposed layout -> coalesced per-class reads in nms_kernel (R5 lesson:
// fusing this into nms explodes FETCH 27->150 MB via 84B-stride reads).
// ---------------------------------------------------------------------------
__global__ __launch_bounds__(256, 4) void score_kernel(
    const float* __restrict__ conf, float* __restrict__ scores) {
  __shared__ __align__(16) float buf[256 * CC];
  const int tid = threadIdx.x;
  const int i0 = blockIdx.x * 256;
  const int base = i0 * CC;
  int total = BB * NN * CC - base;
  if (total > 256 * CC) total = 256 * CC;
  {
    const float4* g4 = (const float4*)(conf + base);
    float4* b4 = (float4*)buf;
    const int n4 = total >> 2;
    for (int t = tid; t < n4; t += 256) b4[t] = g4[t];
  }
  __syncthreads();
  const int i = i0 + tid;
  if (i >= BB * NN) return;
  const float* p = buf + tid * CC;
  float x[CC];
#pragma unroll
  for (int c = 0; c < CC; ++c) x[c] = p[c];
  float m = x[0];
#pragma unroll
  for (int c = 1; c < CC; ++c) m = fmaxf(m, x[c]);
  float e[CC];
#pragma unroll
  for (int c = 0; c < CC; ++c) e[c] = (float)fexp((double)(x[c] - m));
  float r0 = e[0] + e[8], r1 = e[1] + e[9], r2 = e[2] + e[10], r3 = e[3] + e[11];
  float r4 = e[4] + e[12], r5 = e[5] + e[13], r6 = e[6] + e[14], r7 = e[7] + e[15];
  float sum = ((r0 + r1) + (r2 + r3)) + ((r4 + r5) + (r6 + r7));
  sum += e[16]; sum += e[17]; sum += e[18]; sum += e[19]; sum += e[20];
  const int b = i / NN, n = i - b * NN;
#pragma unroll
  for (int c = 0; c < CC; ++c)
    scores[((size_t)b * CC + c) * NN + n] = e[c] / sum;  // true f32 divide
}

__device__ __forceinline__ int score_bin(float s) {
  unsigned u = __float_as_uint(s);
  int bin = (int)(u >> 15) - 30720;
  return bin < 0 ? 0 : (bin > NBINS - 1 ? NBINS - 1 : bin);
}

// Mode-0 fallback: full softmax score for (b,n,c) straight from conf.
__device__ __forceinline__ float score_full(const float* conf, int b, int c, int n) {
  const float* p = conf + ((size_t)b * NN + n) * CC;
  float mm = p[0];
  for (int c2 = 1; c2 < CC; ++c2) mm = fmaxf(mm, p[c2]);
  float e[CC];
  for (int c2 = 0; c2 < CC; ++c2) e[c2] = (float)fexp((double)(p[c2] - mm));
  float r0 = e[0] + e[8], r1 = e[1] + e[9], r2 = e[2] + e[10], r3 = e[3] + e[11];
  float r4 = e[4] + e[12], r5 = e[5] + e[13], r6 = e[6] + e[14], r7 = e[7] + e[15];
  float sum = ((r0 + r1) + (r2 + r3)) + ((r4 + r5) + (r6 + r7));
  sum += e[16]; sum += e[17]; sum += e[18]; sum += e[19]; sum += e[20];
  return e[c] / sum;
}

// ---------------------------------------------------------------------------
// One block per (b,c): single-pass top-200 (histogram + rank-sort, 1 barrier)
// + divide-free exact IoU supp matrix + fast-path greedy + row assembly.
// ---------------------------------------------------------------------------
__global__ __launch_bounds__(256) void nms_kernel(
    const float* __restrict__ loc, const float* __restrict__ conf,
    const float* __restrict__ pose, const float* __restrict__ line,
    const float* __restrict__ dbox, const float* __restrict__ scores,
    int mode, float* __restrict__ out) {
  const int bc = blockIdx.x;
  const int b = bc / CC, c = bc - b * CC;
  const int tid = threadIdx.x;
  const int wv = tid >> 6, lane = tid & 63;
  float* outSlab = out + (size_t)bc * (TOPK * ROWW);
  const float4 z4 = make_float4(0.f, 0.f, 0.f, 0.f);

  if (c == 0) {  // out.at[:, 0].set(0.0)
    float4* o4 = (float4*)outSlab;
    for (int i = tid; i < TOPK * ROWW / 4; i += 256) o4[i] = z4;
    return;
  }

  __shared__ int hist[NBINS];
  __shared__ unsigned long long ckey[CAP];   // (score bits << 32) | ~idx
  __shared__ float4 cbox[TOPK];              // x1,y1,x2,y2 (sorted order)
  __shared__ float carea[TOPK];
  __shared__ float sScore[TOPK];
  __shared__ int sIdx[TOPK];
  __shared__ unsigned long long supp[TOPK * 4];
  __shared__ unsigned long long rowAnyBits[4];
  __shared__ int kept[TOPK];
  __shared__ int waveTot[4];
  __shared__ int sBT, sCnt, sKept;

  for (int i = tid; i < NBINS; i += 256) hist[i] = 0;
  if (tid == 0) { sCnt = 0; sBT = 0; }
  __syncthreads();

  const float* scoresB = scores + ((size_t)b * CC + c) * NN;

  // ---- load scores to registers: 9 independent float4 loads ----
  float4 v[9];
  if (mode == 1) {
#pragma unroll
    for (int k = 0; k < 8; ++k)
      v[k] = *(const float4*)(scoresB + k * 1024 + tid * 4);
    if (tid < 135)  // 8732-8192=540=135*4
      v[8] = *(const float4*)(scoresB + 8192 + tid * 4);
    else
      v[8] = make_float4(-1.f, -1.f, -1.f, -1.f);
  } else {
#pragma unroll 1
    for (int k = 0; k < 9; ++k) {
      const int n0 = k * 1024 + (tid << 2);
      if (k < 8 || tid < 135) {
        v[k].x = score_full(conf, b, c, n0 + 0);
        v[k].y = score_full(conf, b, c, n0 + 1);
        v[k].z = score_full(conf, b, c, n0 + 2);
        v[k].w = score_full(conf, b, c, n0 + 3);
      } else {
        v[k] = make_float4(-1.f, -1.f, -1.f, -1.f);
      }
    }
  }

  // ---- histogram on f32 score bit-pattern (monotone for s>0) ----
#pragma unroll
  for (int k = 0; k < 9; ++k) {
    if (v[k].x > 0.01f) atomicAdd(&hist[score_bin(v[k].x)], 1);
    if (v[k].y > 0.01f) atomicAdd(&hist[score_bin(v[k].y)], 1);
    if (v[k].z > 0.01f) atomicAdd(&hist[score_bin(v[k].z)], 1);
    if (v[k].w > 0.01f) atomicAdd(&hist[score_bin(v[k].w)], 1);
  }
  __syncthreads();

  // ---- parallel threshold-bin: wave suffix-scan + crossing thread ----
  int s8 = 0;
#pragma unroll
  for (int k = 0; k < 8; ++k) s8 += hist[tid * 8 + k];
  int cs = s8;
#pragma unroll
  for (int d = 1; d < 64; d <<= 1) {
    int t = __shfl_down(cs, d, 64);
    if (lane + d < 64) cs += t;
  }
  if (lane == 0) waveTot[wv] = cs;
  __syncthreads();
  {
    int higher = 0;
    for (int g = wv + 1; g < 4; ++g) higher += waveTot[g];
    int incl = cs + higher;
    int excl = incl - s8;
    if (excl < TOPK && incl >= TOPK) {  // unique crossing thread
      int cum = excl, bt = tid * 8;
      for (int bin = tid * 8 + 7;; --bin) {
        cum += hist[bin];
        if (cum >= TOPK || bin == tid * 8) { bt = bin; break; }
      }
      sBT = bt;
    }
  }
  __syncthreads();
  const int bt = sBT;

  // ---- collect candidate keys from registers ----
#pragma unroll
  for (int k = 0; k < 9; ++k) {
    float sv[4] = {v[k].x, v[k].y, v[k].z, v[k].w};
#pragma unroll
    for (int j = 0; j < 4; ++j) {
      float s = sv[j];
      if (s > 0.01f && score_bin(s) >= bt) {
        int p = atomicAdd(&sCnt, 1);
        if (p < CAP) {
          unsigned n = (unsigned)(k * 1024 + (tid << 2) + j);
          ckey[p] = ((unsigned long long)__float_as_uint(s) << 32) |
                    (unsigned long long)(0xFFFFFFFFu - n);
        }
      }
    }
  }
  __syncthreads();
  const int M = sCnt < CAP ? sCnt : CAP;
  if (M == 0) {
    float4* o4 = (float4*)outSlab;
    for (int i = tid; i < TOPK * ROWW / 4; i += 256) o4[i] = z4;
    return;
  }
  const int K = M < TOPK ? M : TOPK;

  // ---- rank-sort: key desc == (score desc, idx asc); unique keys ----
  for (int t = tid; t < M; t += 256) {
    unsigned long long kt = ckey[t];
    int r = 0;
    for (int j = 0; j < M; ++j) r += (ckey[j] > kt) ? 1 : 0;  // LDS broadcast
    if (r < TOPK) {
      sScore[r] = __uint_as_float((unsigned)(kt >> 32));
      sIdx[r] = (int)(0xFFFFFFFFu - (unsigned)(kt & 0xFFFFFFFFull));
    }
  }
  __syncthreads();

  // ---- decode candidate boxes, f32, reference op order ----
  const float* locB = loc + (size_t)b * NN * 4;
  if (tid < K) {
    int n = sIdx[tid];
    float4 l4 = *(const float4*)(locB + (size_t)n * 4);
    float4 d4 = *(const float4*)(dbox + (size_t)n * 4);
    float cx = d4.x + (l4.x * 0.1f) * d4.z;
    float cy = d4.y + (l4.y * 0.1f) * d4.w;
    float w = d4.z * (float)fexp((double)(l4.z * 0.2f));
    float h = d4.w * (float)fexp((double)(l4.w * 0.2f));
    float x1 = cx - w * 0.5f;
    float y1 = cy - h * 0.5f;
    float x2 = x1 + w;
    float y2 = y1 + h;
    cbox[tid] = make_float4(x1, y1, x2, y2);
    carea[tid] = (x2 - x1) * (y2 - y1);
  }
  __syncthreads();

  // ---- supp matrix, divide-free exact IoU compare ----
  // RN_f32(inter/uni) > 0.45f  <=>  fma(-TMID, uni, inter) > 0 in double,
  // TMID = (double)0.45f + 2^-26 (midpoint; tie rounds-to-even -> false both).
  {
    const double TMID = (double)0.45f + 0x1p-26;
    const int l = wv * 64 + lane;
    const bool lvalid = l < K;
    float4 lb = lvalid ? cbox[l] : z4;
    float lar = lvalid ? carea[l] : 0.f;
    const int jlim = (K < wv * 64 + 63) ? K : (wv * 64 + 63);
    for (int j = 0; j < jlim; ++j) {
      float4 jb = cbox[j];             // ds_read_b128 broadcast
      float ja = carea[j];
      float xx1 = fmaxf(lb.x, jb.x);
      float yy1 = fmaxf(lb.y, jb.y);
      float xx2 = fminf(lb.z, jb.z);
      float yy2 = fminf(lb.w, jb.w);
      float iw = fmaxf(xx2 - xx1, 0.0f);
      float ih = fmaxf(yy2 - yy1, 0.0f);
      float inter = iw * ih;
      float uni = (lar - inter) + ja;  // area - inter + area[i]
      double tt = fma(-TMID, (double)uni, (double)inter);
      bool hit = lvalid & (l > j) & (tt > 0.0);
      unsigned long long mres = __ballot((int)hit);
      if (lane == 0) supp[j * 4 + wv] = mres;
    }
    if (lane == 0)
      for (int j = jlim; j < K; ++j) supp[j * 4 + wv] = 0ull;
  }
  __syncthreads();

  // ---- rowAny: which rows suppress anyone (enables fast greedy path) ----
  {
    bool nz = false;
    if (tid < K)
      nz = (supp[tid * 4 + 0] | supp[tid * 4 + 1] |
            supp[tid * 4 + 2] | supp[tid * 4 + 3]) != 0ull;
    unsigned long long bal = __ballot((int)nz);
    if (lane == 0) rowAnyBits[wv] = bal;
  }
  __syncthreads();

  // ---- serial greedy: ffs bit-scan, LDS reads only on suppressing rows ----
  if (tid == 0) {
    unsigned long long alive[4];
#pragma unroll
    for (int w = 0; w < 4; ++w) {
      int cnt = K - w * 64;
      alive[w] = cnt <= 0 ? 0ull : (cnt >= 64 ? ~0ull : ((1ull << cnt) - 1ull));
    }
    int nk = 0;
#pragma unroll
    for (int w = 0; w < 4; ++w) {
      const unsigned long long raw = rowAnyBits[w];
      while (alive[w]) {
        int bit = __ffsll(alive[w]) - 1;
        int j = w * 64 + bit;
        kept[nk++] = j;
        alive[w] &= ~(1ull << bit);
        if ((raw >> bit) & 1) {
          unsigned long long r0 = supp[j * 4 + 0];
          unsigned long long r1 = supp[j * 4 + 1];
          unsigned long long r2 = supp[j * 4 + 2];
          unsigned long long r3 = supp[j * 4 + 3];
          alive[0] &= ~r0; alive[1] &= ~r1; alive[2] &= ~r2; alive[3] &= ~r3;
        }
      }
    }
    sKept = nk;
  }
  __syncthreads();

  // ---- write kept rows, then zero only the tail rows ----
  const int nk = sKept;
  const float* poseB = pose + (size_t)b * NN * NPOSE;
  const float* lineB = line + (size_t)b * NN * NLINE;
  for (int t = tid; t < nk; t += 256) {
    int j = kept[t];
    int n = sIdx[j];
    float* row = outSlab + (size_t)t * ROWW;
    float4 bx = cbox[j];
    row[0] = sScore[j];
    row[1] = bx.x;
    row[2] = bx.y;
    row[3] = bx.z;
    row[4] = bx.w;
    const float4* p4 = (const float4*)(poseB + (size_t)n * NPOSE);
#pragma unroll
    for (int q = 0; q < 8; ++q) {
      float4 pv = p4[q];
      row[5 + 4 * q + 0] = pv.x;
      row[5 + 4 * q + 1] = pv.y;
      row[5 + 4 * q + 2] = pv.z;
      row[5 + 4 * q + 3] = pv.w;
    }
    row[37] = lineB[(size_t)n * NLINE + 0];
    row[38] = lineB[(size_t)n * NLINE + 1];
    row[39] = lineB[(size_t)n * NLINE + 2];
  }
  {  // rows [nk, TOPK): 10 float4 per row
    const int zq = (TOPK - nk) * 10;
    float4* o4 = (float4*)(outSlab + (size_t)nk * ROWW);
    for (int q = tid; q < zq; q += 256) o4[q] = z4;
  }
}

// ---------------------------------------------------------------------------
extern "C" void kernel_launch(void* const* d_in, const int* in_sizes, int n_in,
                              void* d_out, int out_size, void* d_ws, size_t ws_size,
                              hipStream_t stream) {
  const float* loc  = (const float*)d_in[0];
  const float* conf = (const float*)d_in[1];
  const float* pose = (const float*)d_in[2];
  const float* line = (const float*)d_in[3];
  const float* dbox = (const float*)d_in[4];
  float* out = (float*)d_out;

  const size_t scoreBytes = (size_t)BB * CC * NN * sizeof(float);  // ~23.5 MB
  int mode = (ws_size >= scoreBytes) ? 1 : 0;
  float* scores = mode ? (float*)d_ws : nullptr;

  if (mode) {
    const int total = BB * NN;
    score_kernel<<<(total + 255) / 256, 256, 0, stream>>>(conf, scores);
  }
  nms_kernel<<<BB * CC, 256, 0, stream>>>(loc, conf, pose, line, dbox,
                                          scores, mode, out);
}

// Round 8
// 192.016 us; speedup vs baseline: 1.2047x; 1.0108x over previous
//
#include <hip/hip_runtime.h>
#include <math.h>

#define BB 32
#define NN 8732
#define CC 21
#define TOPK 200
#define NPOSE 32
#define NLINE 3
#define NBINS 2048
#define CAP 1024
#define ROWW 40

// ---------------------------------------------------------------------------
// Full-precision f64 exp (degree-12 Horner), |rel err| ~1e-15. Used for the
// per-block table init and the (rare) box-decode exps.
// ---------------------------------------------------------------------------
__device__ __forceinline__ double fexp12(double x) {
  const double LOG2E = 1.4426950408889634074;
  const double LN2HI = 6.93147180369123816490e-01;
  const double LN2LO = 1.90821492927058770002e-10;
  double kd = rint(x * LOG2E);
  double r = fma(-kd, LN2HI, x);
  r = fma(-kd, LN2LO, r);
  double p = 2.08767569878680989792e-09;
  p = fma(p, r, 2.50521083854417187751e-08);
  p = fma(p, r, 2.75573192239858906526e-07);
  p = fma(p, r, 2.75573192239858925110e-06);
  p = fma(p, r, 2.48015873015873015873e-05);
  p = fma(p, r, 1.98412698412698412698e-04);
  p = fma(p, r, 1.38888888888888888889e-03);
  p = fma(p, r, 8.33333333333333333333e-03);
  p = fma(p, r, 4.16666666666666666667e-02);
  p = fma(p, r, 1.66666666666666666667e-01);
  p = fma(p, r, 0.5);
  p = fma(p, r, 1.0);
  p = fma(p, r, 1.0);
  int k = (int)kd;
  k = k < -1020 ? -1020 : (k > 1020 ? 1020 : k);
  double sc = __longlong_as_double((long long)(1023 + k) << 52);
  return p * sc;  // exact pow2 mul == ldexp(p,k)
}

// ---------------------------------------------------------------------------
// Hot-path f64 exp via 64-entry LDS table: exp(x) = 2^(ki>>6)*T[ki&63]*P(r),
// |r| <= ln2/128, degree-4 Horner. |rel err| ~3e-13 -> f32-rounds identically
// to exact exp except ~5e-6 prob/call (1 ulp, harmless off exact ties).
// ---------------------------------------------------------------------------
__device__ __forceinline__ double fexp_t(double x, const double* __restrict__ T) {
  const double INV64 = 1.4426950408889634074 * 64.0;          // 64/ln2
  const double L64HI = 6.93147180369123816490e-01 / 64.0;     // exact /64
  const double L64LO = 1.90821492927058770002e-10 / 64.0;
  double kd = rint(x * INV64);
  double r = fma(-kd, L64HI, x);
  r = fma(-kd, L64LO, r);
  double p = 4.16666666666666666667e-02;       // 1/24
  p = fma(p, r, 1.66666666666666666667e-01);   // 1/6
  p = fma(p, r, 0.5);
  p = fma(p, r, 1.0);
  p = fma(p, r, 1.0);
  int ki = (int)kd;
  double t = T[ki & 63];
  int e = ki >> 6;
  e = e < -1020 ? -1020 : e;
  double sc = __longlong_as_double((long long)(1023 + e) << 52);
  return (t * p) * sc;
}

// ---------------------------------------------------------------------------
// scores[b][c][n] = softmax(conf)[b][n][c]; exact-f32 pipeline (f32 max,
// f32-rounded exp of f32 diff, numpy pairwise-8 sum, true f32 divide).
// Transposed layout -> coalesced per-class reads in nms_kernel.
// ---------------------------------------------------------------------------
__global__ __launch_bounds__(256, 4) void score_kernel(
    const float* __restrict__ conf, float* __restrict__ scores) {
  __shared__ __align__(16) float buf[256 * CC];
  __shared__ double Texp[64];
  const int tid = threadIdx.x;
  const int i0 = blockIdx.x * 256;
  const int base = i0 * CC;
  int total = BB * NN * CC - base;
  if (total > 256 * CC) total = 256 * CC;
  {
    const float4* g4 = (const float4*)(conf + base);
    float4* b4 = (float4*)buf;
    const int n4 = total >> 2;
    for (int t = tid; t < n4; t += 256) b4[t] = g4[t];
  }
  if (tid < 64)  // T[j] = 2^(j/64) = exp(j*ln2/64), full-precision init
    Texp[tid] = fexp12((double)tid * (6.93147180369123816490e-01 / 64.0));
  __syncthreads();
  const int i = i0 + tid;
  if (i >= BB * NN) return;
  const float* p = buf + tid * CC;
  float x[CC];
#pragma unroll
  for (int c = 0; c < CC; ++c) x[c] = p[c];
  float m = x[0];
#pragma unroll
  for (int c = 1; c < CC; ++c) m = fmaxf(m, x[c]);
  float e[CC];
#pragma unroll
  for (int c = 0; c < CC; ++c) e[c] = (float)fexp_t((double)(x[c] - m), Texp);
  float r0 = e[0] + e[8], r1 = e[1] + e[9], r2 = e[2] + e[10], r3 = e[3] + e[11];
  float r4 = e[4] + e[12], r5 = e[5] + e[13], r6 = e[6] + e[14], r7 = e[7] + e[15];
  float sum = ((r0 + r1) + (r2 + r3)) + ((r4 + r5) + (r6 + r7));
  sum += e[16]; sum += e[17]; sum += e[18]; sum += e[19]; sum += e[20];
  const int b = i / NN, n = i - b * NN;
#pragma unroll
  for (int c = 0; c < CC; ++c)
    scores[((size_t)b * CC + c) * NN + n] = e[c] / sum;  // true f32 divide
}

__device__ __forceinline__ int score_bin(float s) {
  unsigned u = __float_as_uint(s);
  int bin = (int)(u >> 15) - 30720;
  return bin < 0 ? 0 : (bin > NBINS - 1 ? NBINS - 1 : bin);
}

// Mode-0 fallback: full softmax score for (b,n,c) straight from conf.
__device__ __forceinline__ float score_full(const float* conf, int b, int c, int n) {
  const float* p = conf + ((size_t)b * NN + n) * CC;
  float mm = p[0];
  for (int c2 = 1; c2 < CC; ++c2) mm = fmaxf(mm, p[c2]);
  float e[CC];
  for (int c2 = 0; c2 < CC; ++c2) e[c2] = (float)fexp12((double)(p[c2] - mm));
  float r0 = e[0] + e[8], r1 = e[1] + e[9], r2 = e[2] + e[10], r3 = e[3] + e[11];
  float r4 = e[4] + e[12], r5 = e[5] + e[13], r6 = e[6] + e[14], r7 = e[7] + e[15];
  float sum = ((r0 + r1) + (r2 + r3)) + ((r4 + r5) + (r6 + r7));
  sum += e[16]; sum += e[17]; sum += e[18]; sum += e[19]; sum += e[20];
  return e[c] / sum;
}

// ---------------------------------------------------------------------------
// One block per (b,c): single-pass top-200 (histogram + chunked rank-sort)
// + chunk-prefetched divide-free IoU supp matrix + fast greedy + rows.
// ---------------------------------------------------------------------------
__global__ __launch_bounds__(256) void nms_kernel(
    const float* __restrict__ loc, const float* __restrict__ conf,
    const float* __restrict__ pose, const float* __restrict__ line,
    const float* __restrict__ dbox, const float* __restrict__ scores,
    int mode, float* __restrict__ out) {
  const int bc = blockIdx.x;
  const int b = bc / CC, c = bc - b * CC;
  const int tid = threadIdx.x;
  const int wv = tid >> 6, lane = tid & 63;
  float* outSlab = out + (size_t)bc * (TOPK * ROWW);
  const float4 z4 = make_float4(0.f, 0.f, 0.f, 0.f);

  if (c == 0) {  // out.at[:, 0].set(0.0)
    float4* o4 = (float4*)outSlab;
    for (int i = tid; i < TOPK * ROWW / 4; i += 256) o4[i] = z4;
    return;
  }

  __shared__ int hist[NBINS];
  __shared__ __align__(16) unsigned long long ckey[CAP + 16];
  __shared__ float4 cbox[TOPK];
  __shared__ float carea[TOPK];
  __shared__ float sScore[TOPK];
  __shared__ int sIdx[TOPK];
  __shared__ unsigned long long supp[TOPK * 4];
  __shared__ unsigned long long rowAnyBits[4];
  __shared__ int kept[TOPK];
  __shared__ int waveTot[4];
  __shared__ int sBT, sCnt, sKept;

  for (int i = tid; i < NBINS; i += 256) hist[i] = 0;
  if (tid == 0) { sCnt = 0; sBT = 0; }
  __syncthreads();

  const float* scoresB = scores + ((size_t)b * CC + c) * NN;

  // ---- load scores to registers: 9 independent float4 loads ----
  float4 v[9];
  if (mode == 1) {
#pragma unroll
    for (int k = 0; k < 8; ++k)
      v[k] = *(const float4*)(scoresB + k * 1024 + tid * 4);
    if (tid < 135)  // 8732-8192=540=135*4
      v[8] = *(const float4*)(scoresB + 8192 + tid * 4);
    else
      v[8] = make_float4(-1.f, -1.f, -1.f, -1.f);
  } else {
#pragma unroll 1
    for (int k = 0; k < 9; ++k) {
      const int n0 = k * 1024 + (tid << 2);
      if (k < 8 || tid < 135) {
        v[k].x = score_full(conf, b, c, n0 + 0);
        v[k].y = score_full(conf, b, c, n0 + 1);
        v[k].z = score_full(conf, b, c, n0 + 2);
        v[k].w = score_full(conf, b, c, n0 + 3);
      } else {
        v[k] = make_float4(-1.f, -1.f, -1.f, -1.f);
      }
    }
  }

  // ---- histogram on f32 score bit-pattern (monotone for s>0) ----
#pragma unroll
  for (int k = 0; k < 9; ++k) {
    if (v[k].x > 0.01f) atomicAdd(&hist[score_bin(v[k].x)], 1);
    if (v[k].y > 0.01f) atomicAdd(&hist[score_bin(v[k].y)], 1);
    if (v[k].z > 0.01f) atomicAdd(&hist[score_bin(v[k].z)], 1);
    if (v[k].w > 0.01f) atomicAdd(&hist[score_bin(v[k].w)], 1);
  }
  __syncthreads();

  // ---- parallel threshold-bin: wave suffix-scan + crossing thread ----
  int s8 = 0;
#pragma unroll
  for (int k = 0; k < 8; ++k) s8 += hist[tid * 8 + k];
  int cs = s8;
#pragma unroll
  for (int d = 1; d < 64; d <<= 1) {
    int t = __shfl_down(cs, d, 64);
    if (lane + d < 64) cs += t;
  }
  if (lane == 0) waveTot[wv] = cs;
  __syncthreads();
  {
    int higher = 0;
    for (int g = wv + 1; g < 4; ++g) higher += waveTot[g];
    int incl = cs + higher;
    int excl = incl - s8;
    if (excl < TOPK && incl >= TOPK) {  // unique crossing thread
      int cum = excl, bt = tid * 8;
      for (int bin = tid * 8 + 7;; --bin) {
        cum += hist[bin];
        if (cum >= TOPK || bin == tid * 8) { bt = bin; break; }
      }
      sBT = bt;
    }
  }
  __syncthreads();
  const int bt = sBT;

  // ---- collect candidate keys from registers ----
#pragma unroll
  for (int k = 0; k < 9; ++k) {
    float sv[4] = {v[k].x, v[k].y, v[k].z, v[k].w};
#pragma unroll
    for (int j = 0; j < 4; ++j) {
      float s = sv[j];
      if (s > 0.01f && score_bin(s) >= bt) {
        int p = atomicAdd(&sCnt, 1);
        if (p < CAP) {
          unsigned n = (unsigned)(k * 1024 + (tid << 2) + j);
          ckey[p] = ((unsigned long long)__float_as_uint(s) << 32) |
                    (unsigned long long)(0xFFFFFFFFu - n);
        }
      }
    }
  }
  __syncthreads();
  const int M = sCnt < CAP ? sCnt : CAP;
  if (M == 0) {
    float4* o4 = (float4*)outSlab;
    for (int i = tid; i < TOPK * ROWW / 4; i += 256) o4[i] = z4;
    return;
  }
  const int K = M < TOPK ? M : TOPK;
  const int Mpad = (M + 15) & ~15;
  for (int i = M + tid; i < Mpad; i += 256) ckey[i] = 0ull;  // pad: rank-neutral
  __syncthreads();

  // ---- rank-sort, 16-keys-per-chunk LDS reads (latency-batched) ----
  for (int t = tid; t < M; t += 256) {
    unsigned long long kt = ckey[t];
    int r = 0;
    for (int j0 = 0; j0 < Mpad; j0 += 16) {
      ulonglong2 kk[8];
#pragma unroll
      for (int q = 0; q < 8; ++q)
        kk[q] = *(const ulonglong2*)(ckey + j0 + 2 * q);
#pragma unroll
      for (int q = 0; q < 8; ++q) {
        r += (kk[q].x > kt) ? 1 : 0;
        r += (kk[q].y > kt) ? 1 : 0;
      }
    }
    if (r < TOPK) {  // keys unique -> ranks unique
      sScore[r] = __uint_as_float((unsigned)(kt >> 32));
      sIdx[r] = (int)(0xFFFFFFFFu - (unsigned)(kt & 0xFFFFFFFFull));
    }
  }
  __syncthreads();

  // ---- decode candidate boxes, f32, reference op order ----
  const float* locB = loc + (size_t)b * NN * 4;
  if (tid < K) {
    int n = sIdx[tid];
    float4 l4 = *(const float4*)(locB + (size_t)n * 4);
    float4 d4 = *(const float4*)(dbox + (size_t)n * 4);
    float cx = d4.x + (l4.x * 0.1f) * d4.z;
    float cy = d4.y + (l4.y * 0.1f) * d4.w;
    float w = d4.z * (float)fexp12((double)(l4.z * 0.2f));
    float h = d4.w * (float)fexp12((double)(l4.w * 0.2f));
    float x1 = cx - w * 0.5f;
    float y1 = cy - h * 0.5f;
    float x2 = x1 + w;
    float y2 = y1 + h;
    cbox[tid] = make_float4(x1, y1, x2, y2);
    carea[tid] = (x2 - x1) * (y2 - y1);
  }
  __syncthreads();

  // ---- supp matrix, 8-row prefetch chunks, divide-free exact IoU ----
  // RN_f32(inter/uni) > 0.45f  <=>  fma(-TMID, uni, inter) > 0 in double,
  // TMID = (double)0.45f + 2^-26 (midpoint; ties round-to-even -> false).
  {
    const double TMID = (double)0.45f + 0x1p-26;
    const int l = wv * 64 + lane;
    const bool lvalid = l < K;
    float4 lb = lvalid ? cbox[l] : z4;
    float lar = lvalid ? carea[l] : 0.f;
    const int jlim = (K < wv * 64 + 63) ? K : (wv * 64 + 63);
    for (int j0 = 0; j0 < jlim; j0 += 8) {
      const int jc = (jlim - j0 < 8) ? (jlim - j0) : 8;
      float4 jb[8];
      float ja[8];
#pragma unroll
      for (int q = 0; q < 8; ++q)
        if (q < jc) { jb[q] = cbox[j0 + q]; ja[q] = carea[j0 + q]; }
      unsigned long long mres[8];
#pragma unroll
      for (int q = 0; q < 8; ++q) {
        if (q < jc) {  // jc wave-uniform
          float xx1 = fmaxf(lb.x, jb[q].x);
          float yy1 = fmaxf(lb.y, jb[q].y);
          float xx2 = fminf(lb.z, jb[q].z);
          float yy2 = fminf(lb.w, jb[q].w);
          float iw = fmaxf(xx2 - xx1, 0.0f);
          float ih = fmaxf(yy2 - yy1, 0.0f);
          float inter = iw * ih;
          float uni = (lar - inter) + ja[q];  // area - inter + area[i]
          double tt = fma(-TMID, (double)uni, (double)inter);
          bool hit = lvalid & (l > (j0 + q)) & (tt > 0.0);
          mres[q] = __ballot((int)hit);
        }
      }
      if (lane == 0) {
#pragma unroll
        for (int q = 0; q < 8; ++q)
          if (q < jc) supp[(j0 + q) * 4 + wv] = mres[q];
      }
    }
    if (lane == 0)
      for (int j = jlim; j < K; ++j) supp[j * 4 + wv] = 0ull;
  }
  __syncthreads();

  // ---- rowAny: which rows suppress anyone (fast greedy path) ----
  {
    bool nz = false;
    if (tid < K)
      nz = (supp[tid * 4 + 0] | supp[tid * 4 + 1] |
            supp[tid * 4 + 2] | supp[tid * 4 + 3]) != 0ull;
    unsigned long long bal = __ballot((int)nz);
    if (lane == 0) rowAnyBits[wv] = bal;
  }
  __syncthreads();

  // ---- serial greedy: ffs bit-scan, LDS reads only on suppressing rows ----
  if (tid == 0) {
    unsigned long long alive[4];
#pragma unroll
    for (int w = 0; w < 4; ++w) {
      int cnt = K - w * 64;
      alive[w] = cnt <= 0 ? 0ull : (cnt >= 64 ? ~0ull : ((1ull << cnt) - 1ull));
    }
    int nk = 0;
#pragma unroll
    for (int w = 0; w < 4; ++w) {
      const unsigned long long raw = rowAnyBits[w];
      while (alive[w]) {
        int bit = __ffsll(alive[w]) - 1;
        int j = w * 64 + bit;
        kept[nk++] = j;
        alive[w] &= ~(1ull << bit);
        if ((raw >> bit) & 1) {
          unsigned long long r0 = supp[j * 4 + 0];
          unsigned long long r1 = supp[j * 4 + 1];
          unsigned long long r2 = supp[j * 4 + 2];
          unsigned long long r3 = supp[j * 4 + 3];
          alive[0] &= ~r0; alive[1] &= ~r1; alive[2] &= ~r2; alive[3] &= ~r3;
        }
      }
    }
    sKept = nk;
  }
  __syncthreads();

  // ---- write kept rows, then zero only the tail rows ----
  const int nk = sKept;
  const float* poseB = pose + (size_t)b * NN * NPOSE;
  const float* lineB = line + (size_t)b * NN * NLINE;
  for (int t = tid; t < nk; t += 256) {
    int j = kept[t];
    int n = sIdx[j];
    float* row = outSlab + (size_t)t * ROWW;
    float4 bx = cbox[j];
    row[0] = sScore[j];
    row[1] = bx.x;
    row[2] = bx.y;
    row[3] = bx.z;
    row[4] = bx.w;
    const float4* p4 = (const float4*)(poseB + (size_t)n * NPOSE);
#pragma unroll
    for (int q = 0; q < 8; ++q) {
      float4 pv = p4[q];
      row[5 + 4 * q + 0] = pv.x;
      row[5 + 4 * q + 1] = pv.y;
      row[5 + 4 * q + 2] = pv.z;
      row[5 + 4 * q + 3] = pv.w;
    }
    row[37] = lineB[(size_t)n * NLINE + 0];
    row[38] = lineB[(size_t)n * NLINE + 1];
    row[39] = lineB[(size_t)n * NLINE + 2];
  }
  {  // rows [nk, TOPK): 10 float4 per row
    const int zq = (TOPK - nk) * 10;
    float4* o4 = (float4*)(outSlab + (size_t)nk * ROWW);
    for (int q = tid; q < zq; q += 256) o4[q] = z4;
  }
}

// ---------------------------------------------------------------------------
extern "C" void kernel_launch(void* const* d_in, const int* in_sizes, int n_in,
                              void* d_out, int out_size, void* d_ws, size_t ws_size,
                              hipStream_t stream) {
  const float* loc  = (const float*)d_in[0];
  const float* conf = (const float*)d_in[1];
  const float* pose = (const float*)d_in[2];
  const float* line = (const float*)d_in[3];
  const float* dbox = (const float*)d_in[4];
  float* out = (float*)d_out;

  const size_t scoreBytes = (size_t)BB * CC * NN * sizeof(float);  // ~23.5 MB
  int mode = (ws_size >= scoreBytes) ? 1 : 0;
  float* scores = mode ? (float*)d_ws : nullptr;

  if (mode) {
    const int total = BB * NN;
    score_kernel<<<(total + 255) / 256, 256, 0, stream>>>(conf, scores);
  }
  nms_kernel<<<BB * CC, 256, 0, stream>>>(loc, conf, pose, line, dbox,
                                          scores, mode, out);
}

// Round 9
// 182.929 us; speedup vs baseline: 1.2645x; 1.0497x over previous
//
#include <hip/hip_runtime.h>
#include <math.h>

#define BB 32
#define NN 8732
#define CC 21
#define TOPK 200
#define NPOSE 32
#define NLINE 3
#define NBINS 2048
#define CAP 1024
#define ROWW 40
#define NT 512   // nms block size: 8 waves -> 2x resident waves vs 256

// ---------------------------------------------------------------------------
// Full-precision f64 exp (degree-12 Horner), |rel err| ~1e-15.
// ---------------------------------------------------------------------------
__device__ __forceinline__ double fexp12(double x) {
  const double LOG2E = 1.4426950408889634074;
  const double LN2HI = 6.93147180369123816490e-01;
  const double LN2LO = 1.90821492927058770002e-10;
  double kd = rint(x * LOG2E);
  double r = fma(-kd, LN2HI, x);
  r = fma(-kd, LN2LO, r);
  double p = 2.08767569878680989792e-09;
  p = fma(p, r, 2.50521083854417187751e-08);
  p = fma(p, r, 2.75573192239858906526e-07);
  p = fma(p, r, 2.75573192239858925110e-06);
  p = fma(p, r, 2.48015873015873015873e-05);
  p = fma(p, r, 1.98412698412698412698e-04);
  p = fma(p, r, 1.38888888888888888889e-03);
  p = fma(p, r, 8.33333333333333333333e-03);
  p = fma(p, r, 4.16666666666666666667e-02);
  p = fma(p, r, 1.66666666666666666667e-01);
  p = fma(p, r, 0.5);
  p = fma(p, r, 1.0);
  p = fma(p, r, 1.0);
  int k = (int)kd;
  k = k < -1020 ? -1020 : (k > 1020 ? 1020 : k);
  double sc = __longlong_as_double((long long)(1023 + k) << 52);
  return p * sc;  // exact pow2 mul == ldexp(p,k)
}

// ---------------------------------------------------------------------------
// Hot-path f64 exp via 64-entry LDS table, |rel err| ~3e-13 (selection-safe).
// ---------------------------------------------------------------------------
__device__ __forceinline__ double fexp_t(double x, const double* __restrict__ T) {
  const double INV64 = 1.4426950408889634074 * 64.0;
  const double L64HI = 6.93147180369123816490e-01 / 64.0;
  const double L64LO = 1.90821492927058770002e-10 / 64.0;
  double kd = rint(x * INV64);
  double r = fma(-kd, L64HI, x);
  r = fma(-kd, L64LO, r);
  double p = 4.16666666666666666667e-02;
  p = fma(p, r, 1.66666666666666666667e-01);
  p = fma(p, r, 0.5);
  p = fma(p, r, 1.0);
  p = fma(p, r, 1.0);
  int ki = (int)kd;
  double t = T[ki & 63];
  int e = ki >> 6;
  e = e < -1020 ? -1020 : e;
  double sc = __longlong_as_double((long long)(1023 + e) << 52);
  return (t * p) * sc;
}

// ---------------------------------------------------------------------------
// scores[b][c][n] = softmax(conf)[b][n][c]; exact-f32 pipeline, transposed.
// ---------------------------------------------------------------------------
__global__ __launch_bounds__(256, 4) void score_kernel(
    const float* __restrict__ conf, float* __restrict__ scores) {
  __shared__ __align__(16) float buf[256 * CC];
  __shared__ double Texp[64];
  const int tid = threadIdx.x;
  const int i0 = blockIdx.x * 256;
  const int base = i0 * CC;
  int total = BB * NN * CC - base;
  if (total > 256 * CC) total = 256 * CC;
  {
    const float4* g4 = (const float4*)(conf + base);
    float4* b4 = (float4*)buf;
    const int n4 = total >> 2;
    for (int t = tid; t < n4; t += 256) b4[t] = g4[t];
  }
  if (tid < 64)
    Texp[tid] = fexp12((double)tid * (6.93147180369123816490e-01 / 64.0));
  __syncthreads();
  const int i = i0 + tid;
  if (i >= BB * NN) return;
  const float* p = buf + tid * CC;
  float x[CC];
#pragma unroll
  for (int c = 0; c < CC; ++c) x[c] = p[c];
  float m = x[0];
#pragma unroll
  for (int c = 1; c < CC; ++c) m = fmaxf(m, x[c]);
  float e[CC];
#pragma unroll
  for (int c = 0; c < CC; ++c) e[c] = (float)fexp_t((double)(x[c] - m), Texp);
  float r0 = e[0] + e[8], r1 = e[1] + e[9], r2 = e[2] + e[10], r3 = e[3] + e[11];
  float r4 = e[4] + e[12], r5 = e[5] + e[13], r6 = e[6] + e[14], r7 = e[7] + e[15];
  float sum = ((r0 + r1) + (r2 + r3)) + ((r4 + r5) + (r6 + r7));
  sum += e[16]; sum += e[17]; sum += e[18]; sum += e[19]; sum += e[20];
  const int b = i / NN, n = i - b * NN;
#pragma unroll
  for (int c = 0; c < CC; ++c)
    scores[((size_t)b * CC + c) * NN + n] = e[c] / sum;  // true f32 divide
}

__device__ __forceinline__ int score_bin(float s) {
  unsigned u = __float_as_uint(s);
  int bin = (int)(u >> 15) - 30720;
  return bin < 0 ? 0 : (bin > NBINS - 1 ? NBINS - 1 : bin);
}

// Mode-0 fallback: full softmax score straight from conf.
__device__ __forceinline__ float score_full(const float* conf, int b, int c, int n) {
  const float* p = conf + ((size_t)b * NN + n) * CC;
  float mm = p[0];
  for (int c2 = 1; c2 < CC; ++c2) mm = fmaxf(mm, p[c2]);
  float e[CC];
  for (int c2 = 0; c2 < CC; ++c2) e[c2] = (float)fexp12((double)(p[c2] - mm));
  float r0 = e[0] + e[8], r1 = e[1] + e[9], r2 = e[2] + e[10], r3 = e[3] + e[11];
  float r4 = e[4] + e[12], r5 = e[5] + e[13], r6 = e[6] + e[14], r7 = e[7] + e[15];
  float sum = ((r0 + r1) + (r2 + r3)) + ((r4 + r5) + (r6 + r7));
  sum += e[16]; sum += e[17]; sum += e[18]; sum += e[19]; sum += e[20];
  return e[c] / sum;
}

// ---------------------------------------------------------------------------
// One 512-thread block per (b,c). Spill-free: only v[5] (20 VGPRs) held
// across phases; batch arrays capped at 4.
// ---------------------------------------------------------------------------
__global__ __launch_bounds__(NT, 4) void nms_kernel(
    const float* __restrict__ loc, const float* __restrict__ conf,
    const float* __restrict__ pose, const float* __restrict__ line,
    const float* __restrict__ dbox, const float* __restrict__ scores,
    int mode, float* __restrict__ out) {
  const int bc = blockIdx.x;
  const int b = bc / CC, c = bc - b * CC;
  const int tid = threadIdx.x;
  const int wv = tid >> 6, lane = tid & 63;
  float* outSlab = out + (size_t)bc * (TOPK * ROWW);
  const float4 z4 = make_float4(0.f, 0.f, 0.f, 0.f);

  if (c == 0) {  // out.at[:, 0].set(0.0)
    float4* o4 = (float4*)outSlab;
    for (int i = tid; i < TOPK * ROWW / 4; i += NT) o4[i] = z4;
    return;
  }

  __shared__ int hist[NBINS];
  __shared__ __align__(16) unsigned long long ckey[CAP + 16];
  __shared__ float4 cbox[TOPK];
  __shared__ float carea[TOPK];
  __shared__ float sScore[TOPK];
  __shared__ int sIdx[TOPK];
  __shared__ unsigned long long supp[TOPK * 4];
  __shared__ unsigned long long rowAnyBits[4];
  __shared__ int kept[TOPK];
  __shared__ int waveTot[8];
  __shared__ int sBT, sCnt, sKept;

  for (int i = tid; i < NBINS; i += NT) hist[i] = 0;
  if (tid == 0) { sCnt = 0; sBT = 0; }
  __syncthreads();

  const float* scoresB = scores + ((size_t)b * CC + c) * NN;

  // ---- load scores: 5 independent float4 loads (17-20 floats/thread) ----
  float4 v[5];
  if (mode == 1) {
#pragma unroll
    for (int k = 0; k < 4; ++k)
      v[k] = *(const float4*)(scoresB + k * 2048 + tid * 4);
    if (tid < 135)  // 8732 - 8192 = 540 = 135*4
      v[4] = *(const float4*)(scoresB + 8192 + tid * 4);
    else
      v[4] = make_float4(-1.f, -1.f, -1.f, -1.f);
  } else {
#pragma unroll 1
    for (int k = 0; k < 5; ++k) {
      const int n0 = (k < 4 ? k * 2048 : 8192) + (tid << 2);
      if (k < 4 || tid < 135) {
        v[k].x = score_full(conf, b, c, n0 + 0);
        v[k].y = score_full(conf, b, c, n0 + 1);
        v[k].z = score_full(conf, b, c, n0 + 2);
        v[k].w = score_full(conf, b, c, n0 + 3);
      } else {
        v[k] = make_float4(-1.f, -1.f, -1.f, -1.f);
      }
    }
  }

  // ---- histogram on f32 score bit-pattern (monotone for s>0) ----
#pragma unroll
  for (int k = 0; k < 5; ++k) {
    if (v[k].x > 0.01f) atomicAdd(&hist[score_bin(v[k].x)], 1);
    if (v[k].y > 0.01f) atomicAdd(&hist[score_bin(v[k].y)], 1);
    if (v[k].z > 0.01f) atomicAdd(&hist[score_bin(v[k].z)], 1);
    if (v[k].w > 0.01f) atomicAdd(&hist[score_bin(v[k].w)], 1);
  }
  __syncthreads();

  // ---- threshold-bin: 4 bins/thread, wave suffix-scan + crossing thread ----
  int s4 = hist[tid * 4] + hist[tid * 4 + 1] + hist[tid * 4 + 2] + hist[tid * 4 + 3];
  int cs = s4;
#pragma unroll
  for (int d = 1; d < 64; d <<= 1) {
    int t = __shfl_down(cs, d, 64);
    if (lane + d < 64) cs += t;
  }
  if (lane == 0) waveTot[wv] = cs;
  __syncthreads();
  {
    int higher = 0;
    for (int g = wv + 1; g < 8; ++g) higher += waveTot[g];
    int incl = cs + higher;
    int excl = incl - s4;
    if (excl < TOPK && incl >= TOPK) {  // unique crossing thread
      int cum = excl, bt = tid * 4;
      for (int bin = tid * 4 + 3;; --bin) {
        cum += hist[bin];
        if (cum >= TOPK || bin == tid * 4) { bt = bin; break; }
      }
      sBT = bt;
    }
  }
  __syncthreads();
  const int bt = sBT;

  // ---- collect candidate keys from registers ----
#pragma unroll
  for (int k = 0; k < 5; ++k) {
    float sv[4] = {v[k].x, v[k].y, v[k].z, v[k].w};
#pragma unroll
    for (int j = 0; j < 4; ++j) {
      float s = sv[j];
      if (s > 0.01f && score_bin(s) >= bt) {
        int p = atomicAdd(&sCnt, 1);
        if (p < CAP) {
          unsigned n = (unsigned)((k < 4 ? k * 2048 : 8192) + (tid << 2) + j);
          ckey[p] = ((unsigned long long)__float_as_uint(s) << 32) |
                    (unsigned long long)(0xFFFFFFFFu - n);
        }
      }
    }
  }
  __syncthreads();
  const int M = sCnt < CAP ? sCnt : CAP;
  if (M == 0) {
    float4* o4 = (float4*)outSlab;
    for (int i = tid; i < TOPK * ROWW / 4; i += NT) o4[i] = z4;
    return;
  }
  const int K = M < TOPK ? M : TOPK;
  const int Mpad = (M + 15) & ~15;
  for (int i = M + tid; i < Mpad; i += NT) ckey[i] = 0ull;  // rank-neutral pad
  __syncthreads();

  // ---- rank-sort: key desc == (score desc, idx asc); 8-key chunks ----
  for (int t = tid; t < M; t += NT) {
    unsigned long long kt = ckey[t];
    int r = 0;
    for (int j0 = 0; j0 < Mpad; j0 += 8) {
      ulonglong2 kk[4];
#pragma unroll
      for (int q = 0; q < 4; ++q)
        kk[q] = *(const ulonglong2*)(ckey + j0 + 2 * q);
#pragma unroll
      for (int q = 0; q < 4; ++q) {
        r += (kk[q].x > kt) ? 1 : 0;
        r += (kk[q].y > kt) ? 1 : 0;
      }
    }
    if (r < TOPK) {  // keys unique -> ranks unique
      sScore[r] = __uint_as_float((unsigned)(kt >> 32));
      sIdx[r] = (int)(0xFFFFFFFFu - (unsigned)(kt & 0xFFFFFFFFull));
    }
  }
  __syncthreads();

  // ---- decode candidate boxes, f32, reference op order ----
  const float* locB = loc + (size_t)b * NN * 4;
  if (tid < K) {
    int n = sIdx[tid];
    float4 l4 = *(const float4*)(locB + (size_t)n * 4);
    float4 d4 = *(const float4*)(dbox + (size_t)n * 4);
    float cx = d4.x + (l4.x * 0.1f) * d4.z;
    float cy = d4.y + (l4.y * 0.1f) * d4.w;
    float w = d4.z * (float)fexp12((double)(l4.z * 0.2f));
    float h = d4.w * (float)fexp12((double)(l4.w * 0.2f));
    float x1 = cx - w * 0.5f;
    float y1 = cy - h * 0.5f;
    float x2 = x1 + w;
    float y2 = y1 + h;
    cbox[tid] = make_float4(x1, y1, x2, y2);
    carea[tid] = (x2 - x1) * (y2 - y1);
  }
  __syncthreads();

  // ---- supp matrix: 8 waves = 4 l-words x 2 j-halves; divide-free IoU ----
  // RN_f32(inter/uni) > 0.45f  <=>  fma(-TMID, uni, inter) > 0 in double,
  // TMID = (double)0.45f + 2^-26 (midpoint; ties round-to-even -> false).
  {
    const double TMID = (double)0.45f + 0x1p-26;
    const int lw = wv & 3, half = wv >> 2;
    const int l = lw * 64 + lane;
    const bool lvalid = l < K;
    float4 lb = lvalid ? cbox[l] : z4;
    float lar = lvalid ? carea[l] : 0.f;
    const int jlim = (K < lw * 64 + 63) ? K : (lw * 64 + 63);
    const int jmid = jlim >> 1;
    const int jstart = half ? jmid : 0;
    const int jend = half ? jlim : jmid;
    for (int j0 = jstart; j0 < jend; j0 += 4) {
      const int jc = (jend - j0 < 4) ? (jend - j0) : 4;
      float4 jb[4];
      float ja[4];
#pragma unroll
      for (int q = 0; q < 4; ++q)
        if (q < jc) { jb[q] = cbox[j0 + q]; ja[q] = carea[j0 + q]; }
      unsigned long long mres[4];
#pragma unroll
      for (int q = 0; q < 4; ++q) {
        if (q < jc) {  // jc wave-uniform
          float xx1 = fmaxf(lb.x, jb[q].x);
          float yy1 = fmaxf(lb.y, jb[q].y);
          float xx2 = fminf(lb.z, jb[q].z);
          float yy2 = fminf(lb.w, jb[q].w);
          float iw = fmaxf(xx2 - xx1, 0.0f);
          float ih = fmaxf(yy2 - yy1, 0.0f);
          float inter = iw * ih;
          float uni = (lar - inter) + ja[q];  // area - inter + area[i]
          double tt = fma(-TMID, (double)uni, (double)inter);
          bool hit = lvalid & (l > (j0 + q)) & (tt > 0.0);
          mres[q] = __ballot((int)hit);
        }
      }
      if (lane == 0) {
#pragma unroll
        for (int q = 0; q < 4; ++q)
          if (q < jc) supp[(j0 + q) * 4 + lw] = mres[q];
      }
    }
    if (half == 1 && lane == 0)
      for (int j = jlim; j < K; ++j) supp[j * 4 + lw] = 0ull;
  }
  __syncthreads();

  // ---- rowAny: which rows suppress anyone (fast greedy path) ----
  if (tid < 256) {
    bool nz = false;
    if (tid < K)
      nz = (supp[tid * 4 + 0] | supp[tid * 4 + 1] |
            supp[tid * 4 + 2] | supp[tid * 4 + 3]) != 0ull;
    unsigned long long bal = __ballot((int)nz);
    if (lane == 0) rowAnyBits[wv] = bal;
  }
  __syncthreads();

  // ---- serial greedy: ffs bit-scan, LDS reads only on suppressing rows ----
  if (tid == 0) {
    unsigned long long alive[4];
#pragma unroll
    for (int w = 0; w < 4; ++w) {
      int cnt = K - w * 64;
      alive[w] = cnt <= 0 ? 0ull : (cnt >= 64 ? ~0ull : ((1ull << cnt) - 1ull));
    }
    int nk = 0;
#pragma unroll
    for (int w = 0; w < 4; ++w) {
      const unsigned long long raw = rowAnyBits[w];
      while (alive[w]) {
        int bit = __ffsll(alive[w]) - 1;
        int j = w * 64 + bit;
        kept[nk++] = j;
        alive[w] &= ~(1ull << bit);
        if ((raw >> bit) & 1) {
          unsigned long long r0 = supp[j * 4 + 0];
          unsigned long long r1 = supp[j * 4 + 1];
          unsigned long long r2 = supp[j * 4 + 2];
          unsigned long long r3 = supp[j * 4 + 3];
          alive[0] &= ~r0; alive[1] &= ~r1; alive[2] &= ~r2; alive[3] &= ~r3;
        }
      }
    }
    sKept = nk;
  }
  __syncthreads();

  // ---- write kept rows, then zero only the tail rows ----
  const int nk = sKept;
  const float* poseB = pose + (size_t)b * NN * NPOSE;
  const float* lineB = line + (size_t)b * NN * NLINE;
  for (int t = tid; t < nk; t += NT) {
    int j = kept[t];
    int n = sIdx[j];
    float* row = outSlab + (size_t)t * ROWW;
    float4 bx = cbox[j];
    row[0] = sScore[j];
    row[1] = bx.x;
    row[2] = bx.y;
    row[3] = bx.z;
    row[4] = bx.w;
    const float4* p4 = (const float4*)(poseB + (size_t)n * NPOSE);
#pragma unroll
    for (int q = 0; q < 8; ++q) {
      float4 pv = p4[q];
      row[5 + 4 * q + 0] = pv.x;
      row[5 + 4 * q + 1] = pv.y;
      row[5 + 4 * q + 2] = pv.z;
      row[5 + 4 * q + 3] = pv.w;
    }
    row[37] = lineB[(size_t)n * NLINE + 0];
    row[38] = lineB[(size_t)n * NLINE + 1];
    row[39] = lineB[(size_t)n * NLINE + 2];
  }
  {  // rows [nk, TOPK): 10 float4 per row
    const int zq = (TOPK - nk) * 10;
    float4* o4 = (float4*)(outSlab + (size_t)nk * ROWW);
    for (int q = tid; q < zq; q += NT) o4[q] = z4;
  }
}

// ---------------------------------------------------------------------------
extern "C" void kernel_launch(void* const* d_in, const int* in_sizes, int n_in,
                              void* d_out, int out_size, void* d_ws, size_t ws_size,
                              hipStream_t stream) {
  const float* loc  = (const float*)d_in[0];
  const float* conf = (const float*)d_in[1];
  const float* pose = (const float*)d_in[2];
  const float* line = (const float*)d_in[3];
  const float* dbox = (const float*)d_in[4];
  float* out = (float*)d_out;

  const size_t scoreBytes = (size_t)BB * CC * NN * sizeof(float);  // ~23.5 MB
  int mode = (ws_size >= scoreBytes) ? 1 : 0;
  float* scores = mode ? (float*)d_ws : nullptr;

  if (mode) {
    const int total = BB * NN;
    score_kernel<<<(total + 255) / 256, 256, 0, stream>>>(conf, scores);
  }
  nms_kernel<<<BB * CC, NT, 0, stream>>>(loc, conf, pose, line, dbox,
                                         scores, mode, out);
}

// Round 10
// 182.418 us; speedup vs baseline: 1.2681x; 1.0028x over previous
//
#include <hip/hip_runtime.h>
#include <math.h>

#define BB 32
#define NN 8732
#define CC 21
#define TOPK 200
#define NPOSE 32
#define NLINE 3
#define NBINS 2048
#define CAP 1024
#define ROWW 40
#define NT 512   // 8 waves/block

// ---------------------------------------------------------------------------
// Full-precision f64 exp (degree-12 Horner), |rel err| ~1e-15.
// ---------------------------------------------------------------------------
__device__ __forceinline__ double fexp12(double x) {
  const double LOG2E = 1.4426950408889634074;
  const double LN2HI = 6.93147180369123816490e-01;
  const double LN2LO = 1.90821492927058770002e-10;
  double kd = rint(x * LOG2E);
  double r = fma(-kd, LN2HI, x);
  r = fma(-kd, LN2LO, r);
  double p = 2.08767569878680989792e-09;
  p = fma(p, r, 2.50521083854417187751e-08);
  p = fma(p, r, 2.75573192239858906526e-07);
  p = fma(p, r, 2.75573192239858925110e-06);
  p = fma(p, r, 2.48015873015873015873e-05);
  p = fma(p, r, 1.98412698412698412698e-04);
  p = fma(p, r, 1.38888888888888888889e-03);
  p = fma(p, r, 8.33333333333333333333e-03);
  p = fma(p, r, 4.16666666666666666667e-02);
  p = fma(p, r, 1.66666666666666666667e-01);
  p = fma(p, r, 0.5);
  p = fma(p, r, 1.0);
  p = fma(p, r, 1.0);
  int k = (int)kd;
  k = k < -1020 ? -1020 : (k > 1020 ? 1020 : k);
  double sc = __longlong_as_double((long long)(1023 + k) << 52);
  return p * sc;  // exact pow2 mul == ldexp(p,k)
}

// ---------------------------------------------------------------------------
// Hot-path f64 exp via 64-entry LDS table, |rel err| ~3e-13 (selection-safe).
// ---------------------------------------------------------------------------
__device__ __forceinline__ double fexp_t(double x, const double* __restrict__ T) {
  const double INV64 = 1.4426950408889634074 * 64.0;
  const double L64HI = 6.93147180369123816490e-01 / 64.0;
  const double L64LO = 1.90821492927058770002e-10 / 64.0;
  double kd = rint(x * INV64);
  double r = fma(-kd, L64HI, x);
  r = fma(-kd, L64LO, r);
  double p = 4.16666666666666666667e-02;
  p = fma(p, r, 1.66666666666666666667e-01);
  p = fma(p, r, 0.5);
  p = fma(p, r, 1.0);
  p = fma(p, r, 1.0);
  int ki = (int)kd;
  double t = T[ki & 63];
  int e = ki >> 6;
  e = e < -1020 ? -1020 : e;
  double sc = __longlong_as_double((long long)(1023 + e) << 52);
  return (t * p) * sc;
}

// ---------------------------------------------------------------------------
// scores[b][c][n] = softmax(conf)[b][n][c]; exact-f32 pipeline, transposed.
// ---------------------------------------------------------------------------
__global__ __launch_bounds__(256, 4) void score_kernel(
    const float* __restrict__ conf, float* __restrict__ scores) {
  __shared__ __align__(16) float buf[256 * CC];
  __shared__ double Texp[64];
  const int tid = threadIdx.x;
  const int i0 = blockIdx.x * 256;
  const int base = i0 * CC;
  int total = BB * NN * CC - base;
  if (total > 256 * CC) total = 256 * CC;
  {
    const float4* g4 = (const float4*)(conf + base);
    float4* b4 = (float4*)buf;
    const int n4 = total >> 2;
    for (int t = tid; t < n4; t += 256) b4[t] = g4[t];
  }
  if (tid < 64)
    Texp[tid] = fexp12((double)tid * (6.93147180369123816490e-01 / 64.0));
  __syncthreads();
  const int i = i0 + tid;
  if (i >= BB * NN) return;
  const float* p = buf + tid * CC;
  float x[CC];
#pragma unroll
  for (int c = 0; c < CC; ++c) x[c] = p[c];
  float m = x[0];
#pragma unroll
  for (int c = 1; c < CC; ++c) m = fmaxf(m, x[c]);
  float e[CC];
#pragma unroll
  for (int c = 0; c < CC; ++c) e[c] = (float)fexp_t((double)(x[c] - m), Texp);
  float r0 = e[0] + e[8], r1 = e[1] + e[9], r2 = e[2] + e[10], r3 = e[3] + e[11];
  float r4 = e[4] + e[12], r5 = e[5] + e[13], r6 = e[6] + e[14], r7 = e[7] + e[15];
  float sum = ((r0 + r1) + (r2 + r3)) + ((r4 + r5) + (r6 + r7));
  sum += e[16]; sum += e[17]; sum += e[18]; sum += e[19]; sum += e[20];
  const int b = i / NN, n = i - b * NN;
#pragma unroll
  for (int c = 0; c < CC; ++c)
    scores[((size_t)b * CC + c) * NN + n] = e[c] / sum;  // true f32 divide
}

__device__ __forceinline__ int score_bin(float s) {
  unsigned u = __float_as_uint(s);
  int bin = (int)(u >> 15) - 30720;
  return bin < 0 ? 0 : (bin > NBINS - 1 ? NBINS - 1 : bin);
}

// Mode-0 fallback: full softmax score straight from conf.
__device__ __forceinline__ float score_full(const float* conf, int b, int c, int n) {
  const float* p = conf + ((size_t)b * NN + n) * CC;
  float mm = p[0];
  for (int c2 = 1; c2 < CC; ++c2) mm = fmaxf(mm, p[c2]);
  float e[CC];
  for (int c2 = 0; c2 < CC; ++c2) e[c2] = (float)fexp12((double)(p[c2] - mm));
  float r0 = e[0] + e[8], r1 = e[1] + e[9], r2 = e[2] + e[10], r3 = e[3] + e[11];
  float r4 = e[4] + e[12], r5 = e[5] + e[13], r6 = e[6] + e[14], r7 = e[7] + e[15];
  float sum = ((r0 + r1) + (r2 + r3)) + ((r4 + r5) + (r6 + r7));
  sum += e[16]; sum += e[17]; sum += e[18]; sum += e[19]; sum += e[20];
  return e[c] / sum;
}

// ---------------------------------------------------------------------------
// One 512-thread block per (b,c). 9-barrier phase chain; gather latency
// overlapped (early-issued loads), decode fused into rank-sort.
// ---------------------------------------------------------------------------
__global__ __launch_bounds__(NT, 4) void nms_kernel(
    const float* __restrict__ loc, const float* __restrict__ conf,
    const float* __restrict__ pose, const float* __restrict__ line,
    const float* __restrict__ dbox, const float* __restrict__ scores,
    int mode, float* __restrict__ out) {
  const int bc = blockIdx.x;
  const int b = bc / CC, c = bc - b * CC;
  const int tid = threadIdx.x;
  const int wv = tid >> 6, lane = tid & 63;
  float* outSlab = out + (size_t)bc * (TOPK * ROWW);
  const float4 z4 = make_float4(0.f, 0.f, 0.f, 0.f);

  if (c == 0) {  // out.at[:, 0].set(0.0)
    float4* o4 = (float4*)outSlab;
    for (int i = tid; i < TOPK * ROWW / 4; i += NT) o4[i] = z4;
    return;
  }

  __shared__ int hist[NBINS];
  __shared__ __align__(16) unsigned long long ckey[CAP + 16];
  __shared__ float4 cbox[TOPK];
  __shared__ float sScore[TOPK];
  __shared__ int sIdx[TOPK];
  __shared__ unsigned long long supp[TOPK * 4];
  __shared__ unsigned long long rowAnyBits[4];
  __shared__ int kept[TOPK];
  __shared__ int waveTot[8];
  __shared__ int sBT, sCnt, sKept;

  const float* scoresB = scores + ((size_t)b * CC + c) * NN;

  // ---- issue score loads FIRST (latency overlaps hist init + barrier) ----
  float4 v[5];
  if (mode == 1) {
#pragma unroll
    for (int k = 0; k < 4; ++k)
      v[k] = *(const float4*)(scoresB + k * 2048 + tid * 4);
    if (tid < 135)  // 8732 - 8192 = 540 = 135*4
      v[4] = *(const float4*)(scoresB + 8192 + tid * 4);
    else
      v[4] = make_float4(-1.f, -1.f, -1.f, -1.f);
  } else {
#pragma unroll 1
    for (int k = 0; k < 5; ++k) {
      const int n0 = (k < 4 ? k * 2048 : 8192) + (tid << 2);
      if (k < 4 || tid < 135) {
        v[k].x = score_full(conf, b, c, n0 + 0);
        v[k].y = score_full(conf, b, c, n0 + 1);
        v[k].z = score_full(conf, b, c, n0 + 2);
        v[k].w = score_full(conf, b, c, n0 + 3);
      } else {
        v[k] = make_float4(-1.f, -1.f, -1.f, -1.f);
      }
    }
  }

  for (int i = tid; i < NBINS; i += NT) hist[i] = 0;
  if (tid == 0) { sCnt = 0; sBT = 0; }
  __syncthreads();

  // ---- histogram on f32 score bit-pattern (monotone for s>0) ----
#pragma unroll
  for (int k = 0; k < 5; ++k) {
    if (v[k].x > 0.01f) atomicAdd(&hist[score_bin(v[k].x)], 1);
    if (v[k].y > 0.01f) atomicAdd(&hist[score_bin(v[k].y)], 1);
    if (v[k].z > 0.01f) atomicAdd(&hist[score_bin(v[k].z)], 1);
    if (v[k].w > 0.01f) atomicAdd(&hist[score_bin(v[k].w)], 1);
  }
  __syncthreads();

  // ---- threshold-bin: 4 bins/thread, wave suffix-scan + crossing thread ----
  int s4 = hist[tid * 4] + hist[tid * 4 + 1] + hist[tid * 4 + 2] + hist[tid * 4 + 3];
  int cs = s4;
#pragma unroll
  for (int d = 1; d < 64; d <<= 1) {
    int t = __shfl_down(cs, d, 64);
    if (lane + d < 64) cs += t;
  }
  if (lane == 0) waveTot[wv] = cs;
  __syncthreads();
  {
    int higher = 0;
    for (int g = wv + 1; g < 8; ++g) higher += waveTot[g];
    int incl = cs + higher;
    int excl = incl - s4;
    if (excl < TOPK && incl >= TOPK) {  // unique crossing thread
      int cum = excl, bt = tid * 4;
      for (int bin = tid * 4 + 3;; --bin) {
        cum += hist[bin];
        if (cum >= TOPK || bin == tid * 4) { bt = bin; break; }
      }
      sBT = bt;
    }
  }
  __syncthreads();
  const int bt = sBT;

  // ---- collect candidate keys from registers ----
#pragma unroll
  for (int k = 0; k < 5; ++k) {
    float sv[4] = {v[k].x, v[k].y, v[k].z, v[k].w};
#pragma unroll
    for (int j = 0; j < 4; ++j) {
      float s = sv[j];
      if (s > 0.01f && score_bin(s) >= bt) {
        int p = atomicAdd(&sCnt, 1);
        if (p < CAP) {
          unsigned n = (unsigned)((k < 4 ? k * 2048 : 8192) + (tid << 2) + j);
          ckey[p] = ((unsigned long long)__float_as_uint(s) << 32) |
                    (unsigned long long)(0xFFFFFFFFu - n);
        }
      }
    }
  }
  __syncthreads();
  const int M = sCnt < CAP ? sCnt : CAP;
  if (M == 0) {
    float4* o4 = (float4*)outSlab;
    for (int i = tid; i < TOPK * ROWW / 4; i += NT) o4[i] = z4;
    return;
  }
  const int K = M < TOPK ? M : TOPK;
  const int Mpad = (M + 15) & ~15;
  for (int i = M + tid; i < Mpad; i += NT) ckey[i] = 0ull;  // rank-neutral pad
  __syncthreads();

  // ---- fused rank-sort + decode: gathers issued before the rank loop, so
  //      their ~900cy latency hides under the LDS compare loop ----
  const float* locB = loc + (size_t)b * NN * 4;
  for (int t = tid; t < M; t += NT) {
    unsigned long long kt = ckey[t];
    unsigned n = 0xFFFFFFFFu - (unsigned)(kt & 0xFFFFFFFFull);
    float4 l4 = *(const float4*)(locB + (size_t)n * 4);   // early issue
    float4 d4 = *(const float4*)(dbox + (size_t)n * 4);   // early issue
    int r = 0;
    for (int j0 = 0; j0 < Mpad; j0 += 8) {
      ulonglong2 kk[4];
#pragma unroll
      for (int q = 0; q < 4; ++q)
        kk[q] = *(const ulonglong2*)(ckey + j0 + 2 * q);
#pragma unroll
      for (int q = 0; q < 4; ++q) {
        r += (kk[q].x > kt) ? 1 : 0;
        r += (kk[q].y > kt) ? 1 : 0;
      }
    }
    if (r < TOPK) {  // keys unique -> ranks unique
      // decode, f32, reference op order
      float cx = d4.x + (l4.x * 0.1f) * d4.z;
      float cy = d4.y + (l4.y * 0.1f) * d4.w;
      float w = d4.z * (float)fexp12((double)(l4.z * 0.2f));
      float h = d4.w * (float)fexp12((double)(l4.w * 0.2f));
      float x1 = cx - w * 0.5f;
      float y1 = cy - h * 0.5f;
      float x2 = x1 + w;
      float y2 = y1 + h;
      cbox[r] = make_float4(x1, y1, x2, y2);
      sScore[r] = __uint_as_float((unsigned)(kt >> 32));
      sIdx[r] = (int)n;
    }
  }
  __syncthreads();

  // ---- supp matrix: 8 waves = 4 l-words x 2 j-halves; divide-free IoU ----
  // RN_f32(inter/uni) > 0.45f  <=>  fma(-TMID, uni, inter) > 0 in double,
  // TMID = (double)0.45f + 2^-26 (midpoint; ties round-to-even -> false).
  // Areas recomputed from boxes: bit-identical to reference's area values.
  {
    const double TMID = (double)0.45f + 0x1p-26;
    const int lw = wv & 3, half = wv >> 2;
    const int l = lw * 64 + lane;
    const bool lvalid = l < K;
    float4 lb = lvalid ? cbox[l] : z4;
    float lar = (lb.z - lb.x) * (lb.w - lb.y);
    const int jlim = (K < lw * 64 + 63) ? K : (lw * 64 + 63);
    const int jmid = jlim >> 1;
    const int jstart = half ? jmid : 0;
    const int jend = half ? jlim : jmid;
    for (int j0 = jstart; j0 < jend; j0 += 4) {
      const int jc = (jend - j0 < 4) ? (jend - j0) : 4;
      float4 jb[4];
#pragma unroll
      for (int q = 0; q < 4; ++q)
        if (q < jc) jb[q] = cbox[j0 + q];
      unsigned long long mres[4];
#pragma unroll
      for (int q = 0; q < 4; ++q) {
        if (q < jc) {  // jc wave-uniform
          float ja = (jb[q].z - jb[q].x) * (jb[q].w - jb[q].y);
          float xx1 = fmaxf(lb.x, jb[q].x);
          float yy1 = fmaxf(lb.y, jb[q].y);
          float xx2 = fminf(lb.z, jb[q].z);
          float yy2 = fminf(lb.w, jb[q].w);
          float iw = fmaxf(xx2 - xx1, 0.0f);
          float ih = fmaxf(yy2 - yy1, 0.0f);
          float inter = iw * ih;
          float uni = (lar - inter) + ja;  // area - inter + area[i]
          double tt = fma(-TMID, (double)uni, (double)inter);
          bool hit = lvalid & (l > (j0 + q)) & (tt > 0.0);
          mres[q] = __ballot((int)hit);
        }
      }
      if (lane == 0) {
#pragma unroll
        for (int q = 0; q < 4; ++q)
          if (q < jc) supp[(j0 + q) * 4 + lw] = mres[q];
      }
    }
    if (half == 1 && lane == 0)
      for (int j = jlim; j < K; ++j) supp[j * 4 + lw] = 0ull;
  }
  __syncthreads();

  // ---- rowAny: which rows suppress anyone (fast greedy path) ----
  if (tid < 256) {
    bool nz = false;
    if (tid < K)
      nz = (supp[tid * 4 + 0] | supp[tid * 4 + 1] |
            supp[tid * 4 + 2] | supp[tid * 4 + 3]) != 0ull;
    unsigned long long bal = __ballot((int)nz);
    if (lane == 0) rowAnyBits[wv] = bal;
  }
  __syncthreads();

  // ---- serial greedy: ffs bit-scan, LDS reads only on suppressing rows ----
  if (tid == 0) {
    unsigned long long alive[4];
#pragma unroll
    for (int w = 0; w < 4; ++w) {
      int cnt = K - w * 64;
      alive[w] = cnt <= 0 ? 0ull : (cnt >= 64 ? ~0ull : ((1ull << cnt) - 1ull));
    }
    int nk = 0;
#pragma unroll
    for (int w = 0; w < 4; ++w) {
      const unsigned long long raw = rowAnyBits[w];
      while (alive[w]) {
        int bit = __ffsll(alive[w]) - 1;
        int j = w * 64 + bit;
        kept[nk++] = j;
        alive[w] &= ~(1ull << bit);
        if ((raw >> bit) & 1) {
          unsigned long long r0 = supp[j * 4 + 0];
          unsigned long long r1 = supp[j * 4 + 1];
          unsigned long long r2 = supp[j * 4 + 2];
          unsigned long long r3 = supp[j * 4 + 3];
          alive[0] &= ~r0; alive[1] &= ~r1; alive[2] &= ~r2; alive[3] &= ~r3;
        }
      }
    }
    sKept = nk;
  }
  __syncthreads();

  // ---- write kept rows, then zero only the tail rows ----
  const int nk = sKept;
  const float* poseB = pose + (size_t)b * NN * NPOSE;
  const float* lineB = line + (size_t)b * NN * NLINE;
  for (int t = tid; t < nk; t += NT) {
    int j = kept[t];
    int n = sIdx[j];
    float* row = outSlab + (size_t)t * ROWW;
    float4 bx = cbox[j];
    const float4* p4 = (const float4*)(poseB + (size_t)n * NPOSE);  // early
    float l0 = lineB[(size_t)n * NLINE + 0];
    float l1 = lineB[(size_t)n * NLINE + 1];
    float l2 = lineB[(size_t)n * NLINE + 2];
    row[0] = sScore[j];
    row[1] = bx.x;
    row[2] = bx.y;
    row[3] = bx.z;
    row[4] = bx.w;
#pragma unroll
    for (int q = 0; q < 8; ++q) {
      float4 pv = p4[q];
      row[5 + 4 * q + 0] = pv.x;
      row[5 + 4 * q + 1] = pv.y;
      row[5 + 4 * q + 2] = pv.z;
      row[5 + 4 * q + 3] = pv.w;
    }
    row[37] = l0;
    row[38] = l1;
    row[39] = l2;
  }
  {  // rows [nk, TOPK): 10 float4 per row
    const int zq = (TOPK - nk) * 10;
    float4* o4 = (float4*)(outSlab + (size_t)nk * ROWW);
    for (int q = tid; q < zq; q += NT) o4[q] = z4;
  }
}

// ---------------------------------------------------------------------------
extern "C" void kernel_launch(void* const* d_in, const int* in_sizes, int n_in,
                              void* d_out, int out_size, void* d_ws, size_t ws_size,
                              hipStream_t stream) {
  const float* loc  = (const float*)d_in[0];
  const float* conf = (const float*)d_in[1];
  const float* pose = (const float*)d_in[2];
  const float* line = (const float*)d_in[3];
  const float* dbox = (const float*)d_in[4];
  float* out = (float*)d_out;

  const size_t scoreBytes = (size_t)BB * CC * NN * sizeof(float);  // ~23.5 MB
  int mode = (ws_size >= scoreBytes) ? 1 : 0;
  float* scores = mode ? (float*)d_ws : nullptr;

  if (mode) {
    const int total = BB * NN;
    score_kernel<<<(total + 255) / 256, 256, 0, stream>>>(conf, scores);
  }
  nms_kernel<<<BB * CC, NT, 0, stream>>>(loc, conf, pose, line, dbox,
                                         scores, mode, out);
}